// Round 1
// baseline (2041.508 us; speedup 1.0000x reference)
//
#include <hip/hip_runtime.h>
#include <hip/hip_bf16.h>

typedef unsigned int u32;
typedef unsigned short u16;

#define COUT 128
#define GSEG 30000
#define BN_EPS 1e-3f

__device__ __forceinline__ u32 f2bf(float x) {
    u32 u = __float_as_uint(x);
    return (u + 0x7fffu + ((u >> 16) & 1u)) >> 16;   // RNE bf16
}

__device__ __forceinline__ void unpack8(uint4 v, float* f) {
    f[0] = __uint_as_float(v.x << 16); f[1] = __uint_as_float(v.x & 0xffff0000u);
    f[2] = __uint_as_float(v.y << 16); f[3] = __uint_as_float(v.y & 0xffff0000u);
    f[4] = __uint_as_float(v.z << 16); f[5] = __uint_as_float(v.z & 0xffff0000u);
    f[6] = __uint_as_float(v.w << 16); f[7] = __uint_as_float(v.w & 0xffff0000u);
}

// ---------------- K1: lin = feat_all @ W + b  (store bf16) + BN1 stats ----------
__global__ __launch_bounds__(256) void k_gemm_bn1(
    const float* __restrict__ A, const float* __restrict__ W,
    const float* __restrict__ bias, u16* __restrict__ lin,
    float* __restrict__ sum1, float* __restrict__ sumsq1, int n)
{
    __shared__ float sW[64 * 128];      // [k][c]
    __shared__ float sA[64 * 68];       // [r][k], stride 68 (16B-aligned, conflict-free)
    __shared__ float sSum[128];
    __shared__ float sSq[128];
    const int t = threadIdx.x;
    const int row0 = blockIdx.x * 64;

    for (int i = t * 4; i < 8192; i += 1024)
        *(float4*)&sW[i] = *(const float4*)&W[i];
    for (int i = t; i < 1024; i += 256) {
        int r = i >> 4;
        int k0 = (i & 15) << 2;
        float4 v = make_float4(0.f, 0.f, 0.f, 0.f);
        if (row0 + r < n) v = *(const float4*)&A[(size_t)(row0 + r) * 64 + k0];
        *(float4*)&sA[r * 68 + k0] = v;
    }
    if (t < 128) { sSum[t] = 0.f; sSq[t] = 0.f; }
    __syncthreads();

    const int tx = t & 15, ty = t >> 4;
    const int c0 = tx * 8;
    float acc[4][8];
#pragma unroll
    for (int i = 0; i < 4; i++)
#pragma unroll
        for (int j = 0; j < 8; j++) acc[i][j] = 0.f;

    for (int k = 0; k < 64; ++k) {
        float4 b0 = *(float4*)&sW[k * 128 + c0];
        float4 b1 = *(float4*)&sW[k * 128 + c0 + 4];
        float bb[8] = {b0.x, b0.y, b0.z, b0.w, b1.x, b1.y, b1.z, b1.w};
#pragma unroll
        for (int i = 0; i < 4; i++) {
            float a = sA[(ty * 4 + i) * 68 + k];
#pragma unroll
            for (int j = 0; j < 8; j++) acc[i][j] = fmaf(a, bb[j], acc[i][j]);
        }
    }

    float4 bv0 = *(const float4*)&bias[c0];
    float4 bv1 = *(const float4*)&bias[c0 + 4];
    float bvv[8] = {bv0.x, bv0.y, bv0.z, bv0.w, bv1.x, bv1.y, bv1.z, bv1.w};
    float ssum[8], ssq[8];
#pragma unroll
    for (int j = 0; j < 8; j++) { ssum[j] = 0.f; ssq[j] = 0.f; }

#pragma unroll
    for (int i = 0; i < 4; i++) {
        int row = row0 + ty * 4 + i;
        if (row >= n) break;
        u32 p[4];
#pragma unroll
        for (int j = 0; j < 8; j++) {
            float v = acc[i][j] + bvv[j];
            ssum[j] += v;
            ssq[j] += v * v;
            acc[i][j] = v;
        }
#pragma unroll
        for (int j = 0; j < 4; j++)
            p[j] = f2bf(acc[i][2 * j]) | (f2bf(acc[i][2 * j + 1]) << 16);
        uint4 sv; sv.x = p[0]; sv.y = p[1]; sv.z = p[2]; sv.w = p[3];
        *(uint4*)(lin + (size_t)row * 128 + c0) = sv;
    }
#pragma unroll
    for (int j = 0; j < 8; j++) {
        atomicAdd(&sSum[c0 + j], ssum[j]);
        atomicAdd(&sSq[c0 + j], ssq[j]);
    }
    __syncthreads();
    if (t < 128) { atomicAdd(&sum1[t], sSum[t]); atomicAdd(&sumsq1[t], sSq[t]); }
}

// ---------------- finalize BN params ----------------
__global__ void k_fin(const float* __restrict__ sum, const float* __restrict__ sumsq,
                      const float* __restrict__ g, const float* __restrict__ be,
                      float* __restrict__ scale, float* __restrict__ shift, float inv_n)
{
    int c = threadIdx.x;
    float mean = sum[c] * inv_n;
    float var = sumsq[c] * inv_n - mean * mean;
    float sc = g[c] * rsqrtf(var + BN_EPS);
    scale[c] = sc;
    shift[c] = be[c] - mean * sc;
}

// ---------------- K2: scatter pw1*feat into feat_add (fp32 atomics) -------------
__global__ __launch_bounds__(256) void k_scatter(
    const u16* __restrict__ lin, const float* __restrict__ xyz, const int* __restrict__ unq,
    const float* __restrict__ scale1, const float* __restrict__ shift1,
    const float* __restrict__ Wp1, const float* __restrict__ bp1,
    float* __restrict__ feat_add, int n)
{
    __shared__ float sS[128], sH[128], sW3[384], sB[128];
    int t = threadIdx.x;
    if (t < 128) {
        sS[t] = scale1[t]; sH[t] = shift1[t]; sB[t] = bp1[t];
        sW3[t] = Wp1[t]; sW3[128 + t] = Wp1[128 + t]; sW3[256 + t] = Wp1[256 + t];
    }
    __syncthreads();
    int row = blockIdx.x * 16 + (t >> 4);
    if (row >= n) return;
    int c0 = (t & 15) * 8;
    uint4 l8 = *(const uint4*)(lin + (size_t)row * 128 + c0);
    float f[8];
    unpack8(l8, f);
    float px = floorf(xyz[row * 3 + 0]);
    float py = floorf(xyz[row * 3 + 1]);
    float pz = floorf(xyz[row * 3 + 2]);
    int g = unq[row];
    float* fa = feat_add + (size_t)g * 128 + c0;
#pragma unroll
    for (int j = 0; j < 8; j++) {
        int c = c0 + j;
        float fe = fmaf(f[j], sS[c], sH[c]);
        float pw = fmaf(px, sW3[c], fmaf(py, sW3[128 + c], fmaf(pz, sW3[256 + c], sB[c])));
        atomicAdd(&fa[j], pw * fe);
    }
}

// ---------------- K3: BN2 stats over out_pre = pw2*feat - feat_add[unq] ---------
__global__ __launch_bounds__(256) void k_stats2(
    const u16* __restrict__ lin, const float* __restrict__ xyz, const int* __restrict__ unq,
    const float* __restrict__ scale1, const float* __restrict__ shift1,
    const float* __restrict__ Wp2, const float* __restrict__ bp2,
    const float* __restrict__ feat_add,
    float* __restrict__ sum2, float* __restrict__ sumsq2, int n, int iters)
{
    __shared__ float sS[128], sH[128], sW3[384], sB[128], sSum[128], sSq[128];
    int t = threadIdx.x;
    if (t < 128) {
        sS[t] = scale1[t]; sH[t] = shift1[t]; sB[t] = bp2[t];
        sW3[t] = Wp2[t]; sW3[128 + t] = Wp2[128 + t]; sW3[256 + t] = Wp2[256 + t];
        sSum[t] = 0.f; sSq[t] = 0.f;
    }
    __syncthreads();
    int c0 = (t & 15) * 8;
    float ssum[8], ssq[8];
#pragma unroll
    for (int j = 0; j < 8; j++) { ssum[j] = 0.f; ssq[j] = 0.f; }

    for (int it = 0; it < iters; ++it) {
        int row = (blockIdx.x * iters + it) * 16 + (t >> 4);
        if (row >= n) break;
        uint4 l8 = *(const uint4*)(lin + (size_t)row * 128 + c0);
        float f[8];
        unpack8(l8, f);
        float px = floorf(xyz[row * 3 + 0]);
        float py = floorf(xyz[row * 3 + 1]);
        float pz = floorf(xyz[row * 3 + 2]);
        int g = unq[row];
        const float4* fa = (const float4*)(feat_add + (size_t)g * 128 + c0);
        float4 fa0 = fa[0], fa1 = fa[1];
        float fav[8] = {fa0.x, fa0.y, fa0.z, fa0.w, fa1.x, fa1.y, fa1.z, fa1.w};
#pragma unroll
        for (int j = 0; j < 8; j++) {
            int c = c0 + j;
            float fe = fmaf(f[j], sS[c], sH[c]);
            float pw = fmaf(px, sW3[c], fmaf(py, sW3[128 + c], fmaf(pz, sW3[256 + c], sB[c])));
            float o = pw * fe - fav[j];
            ssum[j] += o;
            ssq[j] += o * o;
        }
    }
#pragma unroll
    for (int j = 0; j < 8; j++) {
        atomicAdd(&sSum[c0 + j], ssum[j]);
        atomicAdd(&sSq[c0 + j], ssq[j]);
    }
    __syncthreads();
    if (t < 128) { atomicAdd(&sum2[t], sSum[t]); atomicAdd(&sumsq2[t], sSq[t]); }
}

// ---------------- K4: final out = relu(bn2(out_pre)) ----------------------------
__global__ __launch_bounds__(256) void k_final(
    const u16* __restrict__ lin, const float* __restrict__ xyz, const int* __restrict__ unq,
    const float* __restrict__ scale1, const float* __restrict__ shift1,
    const float* __restrict__ Wp2, const float* __restrict__ bp2,
    const float* __restrict__ feat_add,
    const float* __restrict__ scale2, const float* __restrict__ shift2,
    float* __restrict__ out, int n)
{
    __shared__ float sS[128], sH[128], sW3[384], sB[128], sS2[128], sH2[128];
    int t = threadIdx.x;
    if (t < 128) {
        sS[t] = scale1[t]; sH[t] = shift1[t]; sB[t] = bp2[t];
        sW3[t] = Wp2[t]; sW3[128 + t] = Wp2[128 + t]; sW3[256 + t] = Wp2[256 + t];
        sS2[t] = scale2[t]; sH2[t] = shift2[t];
    }
    __syncthreads();
    int row = blockIdx.x * 16 + (t >> 4);
    if (row >= n) return;
    int c0 = (t & 15) * 8;
    uint4 l8 = *(const uint4*)(lin + (size_t)row * 128 + c0);
    float f[8];
    unpack8(l8, f);
    float px = floorf(xyz[row * 3 + 0]);
    float py = floorf(xyz[row * 3 + 1]);
    float pz = floorf(xyz[row * 3 + 2]);
    int g = unq[row];
    const float4* fa = (const float4*)(feat_add + (size_t)g * 128 + c0);
    float4 fa0 = fa[0], fa1 = fa[1];
    float fav[8] = {fa0.x, fa0.y, fa0.z, fa0.w, fa1.x, fa1.y, fa1.z, fa1.w};
    float o[8];
#pragma unroll
    for (int j = 0; j < 8; j++) {
        int c = c0 + j;
        float fe = fmaf(f[j], sS[c], sH[c]);
        float pw = fmaf(px, sW3[c], fmaf(py, sW3[128 + c], fmaf(pz, sW3[256 + c], sB[c])));
        float v = pw * fe - fav[j];
        v = fmaf(v, sS2[c], sH2[c]);
        o[j] = v > 0.f ? v : 0.f;
    }
    float4 s0, s1;
    s0.x = o[0]; s0.y = o[1]; s0.z = o[2]; s0.w = o[3];
    s1.x = o[4]; s1.y = o[5]; s1.z = o[6]; s1.w = o[7];
    float* op = out + (size_t)row * 128 + c0;
    *(float4*)op = s0;
    *(float4*)(op + 4) = s1;
}

extern "C" void kernel_launch(void* const* d_in, const int* in_sizes, int n_in,
                              void* d_out, int out_size, void* d_ws, size_t ws_size,
                              hipStream_t stream)
{
    const float* xyz      = (const float*)d_in[0];
    const float* feat_all = (const float*)d_in[1];
    const int*   unq      = (const int*)d_in[2];
    const float* W_pre    = (const float*)d_in[3];
    const float* b_pre    = (const float*)d_in[4];
    const float* g1       = (const float*)d_in[5];
    const float* be1      = (const float*)d_in[6];
    const float* Wp1      = (const float*)d_in[7];
    const float* bp1      = (const float*)d_in[8];
    const float* Wp2      = (const float*)d_in[9];
    const float* bp2      = (const float*)d_in[10];
    const float* g2       = (const float*)d_in[11];
    const float* be2      = (const float*)d_in[12];
    (void)n_in; (void)out_size;

    const int n = in_sizes[0] / 3;   // 400000

    char* ws = (char*)d_ws;
    float* stats  = (float*)ws;                 // 1024 floats
    float* sum1   = stats;       float* sumsq1 = stats + 128;
    float* sum2   = stats + 256; float* sumsq2 = stats + 384;
    float* scale1 = stats + 512; float* shift1 = stats + 640;
    float* scale2 = stats + 768; float* shift2 = stats + 896;
    const size_t fa_bytes = (size_t)GSEG * 128 * 4;      // 15,360,000
    float* feat_add = (float*)(ws + 4096);
    u16*   lin      = (u16*)(ws + 4096 + fa_bytes);      // 102,400,000 bytes
    (void)ws_size;

    hipMemsetAsync(d_ws, 0, 4096 + fa_bytes, stream);

    k_gemm_bn1<<<(n + 63) / 64, 256, 0, stream>>>(feat_all, W_pre, b_pre, lin, sum1, sumsq1, n);
    k_fin<<<1, 128, 0, stream>>>(sum1, sumsq1, g1, be1, scale1, shift1, 1.0f / n);
    k_scatter<<<(n + 15) / 16, 256, 0, stream>>>(lin, xyz, unq, scale1, shift1, Wp1, bp1, feat_add, n);
    int iters = (n + 16 * 2500 - 1) / (16 * 2500);
    k_stats2<<<2500, 256, 0, stream>>>(lin, xyz, unq, scale1, shift1, Wp2, bp2, feat_add, sum2, sumsq2, n, iters);
    k_fin<<<1, 128, 0, stream>>>(sum2, sumsq2, g2, be2, scale2, shift2, 1.0f / n);
    k_final<<<(n + 15) / 16, 256, 0, stream>>>(lin, xyz, unq, scale1, shift1, Wp2, bp2, feat_add, scale2, shift2, (float*)d_out, n);
}

// Round 2
// 808.989 us; speedup vs baseline: 2.5235x; 2.5235x over previous
//
#include <hip/hip_runtime.h>
#include <hip/hip_bf16.h>

typedef unsigned int u32;
typedef unsigned short u16;

#define COUT 128
#define GSEG 30000
#define BN_EPS 1e-3f

__device__ __forceinline__ u32 f2bf(float x) {
    u32 u = __float_as_uint(x);
    return (u + 0x7fffu + ((u >> 16) & 1u)) >> 16;   // RNE bf16
}

__device__ __forceinline__ void unpack8(uint4 v, float* f) {
    f[0] = __uint_as_float(v.x << 16); f[1] = __uint_as_float(v.x & 0xffff0000u);
    f[2] = __uint_as_float(v.y << 16); f[3] = __uint_as_float(v.y & 0xffff0000u);
    f[4] = __uint_as_float(v.z << 16); f[5] = __uint_as_float(v.z & 0xffff0000u);
    f[6] = __uint_as_float(v.w << 16); f[7] = __uint_as_float(v.w & 0xffff0000u);
}

// ---------------- K1: lin = feat_all @ W + b  (store bf16) + BN1 stats ----------
__global__ __launch_bounds__(256) void k_gemm_bn1(
    const float* __restrict__ A, const float* __restrict__ W,
    const float* __restrict__ bias, u16* __restrict__ lin,
    float* __restrict__ sum1, float* __restrict__ sumsq1, int n)
{
    __shared__ float sW[64 * 128];      // [k][c]
    __shared__ float sA[64 * 68];       // [r][k], stride 68
    __shared__ float sSum[128];
    __shared__ float sSq[128];
    const int t = threadIdx.x;
    const int row0 = blockIdx.x * 64;

    for (int i = t * 4; i < 8192; i += 1024)
        *(float4*)&sW[i] = *(const float4*)&W[i];
    for (int i = t; i < 1024; i += 256) {
        int r = i >> 4;
        int k0 = (i & 15) << 2;
        float4 v = make_float4(0.f, 0.f, 0.f, 0.f);
        if (row0 + r < n) v = *(const float4*)&A[(size_t)(row0 + r) * 64 + k0];
        *(float4*)&sA[r * 68 + k0] = v;
    }
    if (t < 128) { sSum[t] = 0.f; sSq[t] = 0.f; }
    __syncthreads();

    const int tx = t & 15, ty = t >> 4;
    const int c0 = tx * 8;
    float acc[4][8];
#pragma unroll
    for (int i = 0; i < 4; i++)
#pragma unroll
        for (int j = 0; j < 8; j++) acc[i][j] = 0.f;

    for (int k = 0; k < 64; ++k) {
        float4 b0 = *(float4*)&sW[k * 128 + c0];
        float4 b1 = *(float4*)&sW[k * 128 + c0 + 4];
        float bb[8] = {b0.x, b0.y, b0.z, b0.w, b1.x, b1.y, b1.z, b1.w};
#pragma unroll
        for (int i = 0; i < 4; i++) {
            float a = sA[(ty * 4 + i) * 68 + k];
#pragma unroll
            for (int j = 0; j < 8; j++) acc[i][j] = fmaf(a, bb[j], acc[i][j]);
        }
    }

    float4 bv0 = *(const float4*)&bias[c0];
    float4 bv1 = *(const float4*)&bias[c0 + 4];
    float bvv[8] = {bv0.x, bv0.y, bv0.z, bv0.w, bv1.x, bv1.y, bv1.z, bv1.w};
    float ssum[8], ssq[8];
#pragma unroll
    for (int j = 0; j < 8; j++) { ssum[j] = 0.f; ssq[j] = 0.f; }

#pragma unroll
    for (int i = 0; i < 4; i++) {
        int row = row0 + ty * 4 + i;
        if (row >= n) break;
        u32 p[4];
#pragma unroll
        for (int j = 0; j < 8; j++) {
            float v = acc[i][j] + bvv[j];
            ssum[j] += v;
            ssq[j] += v * v;
            acc[i][j] = v;
        }
#pragma unroll
        for (int j = 0; j < 4; j++)
            p[j] = f2bf(acc[i][2 * j]) | (f2bf(acc[i][2 * j + 1]) << 16);
        uint4 sv; sv.x = p[0]; sv.y = p[1]; sv.z = p[2]; sv.w = p[3];
        *(uint4*)(lin + (size_t)row * 128 + c0) = sv;
    }
#pragma unroll
    for (int j = 0; j < 8; j++) {
        atomicAdd(&sSum[c0 + j], ssum[j]);
        atomicAdd(&sSq[c0 + j], ssq[j]);
    }
    __syncthreads();
    if (t < 128) { atomicAdd(&sum1[t], sSum[t]); atomicAdd(&sumsq1[t], sSq[t]); }
}

// ---------------- finalize BN params ----------------
__global__ void k_fin(const float* __restrict__ sum, const float* __restrict__ sumsq,
                      const float* __restrict__ g, const float* __restrict__ be,
                      float* __restrict__ scale, float* __restrict__ shift, float inv_n)
{
    int c = threadIdx.x;
    float mean = sum[c] * inv_n;
    float var = sumsq[c] * inv_n - mean * mean;
    float sc = g[c] * rsqrtf(var + BN_EPS);
    scale[c] = sc;
    shift[c] = be[c] - mean * sc;
}

// ---------------- K2a: histogram of segment ids ----------------
__global__ __launch_bounds__(256) void k_hist(const int* __restrict__ unq,
                                              int* __restrict__ cnt, int n)
{
    int i = blockIdx.x * 256 + threadIdx.x;
    if (i < n) atomicAdd(&cnt[unq[i]], 1);
}

// ---------------- K2b: exclusive scan over 30000 counts (single block) ---------
__global__ __launch_bounds__(1024) void k_scan(const int* __restrict__ cnt,
                                               int* __restrict__ offs,
                                               int* __restrict__ cursor)
{
    __shared__ int sdata[1024];
    __shared__ int sbase;
    int t = threadIdx.x;
    if (t == 0) sbase = 0;
    __syncthreads();
    for (int base = 0; base < GSEG; base += 1024) {
        int i = base + t;
        int v = (i < GSEG) ? cnt[i] : 0;
        sdata[t] = v;
        __syncthreads();
        for (int d = 1; d < 1024; d <<= 1) {
            int add = (t >= d) ? sdata[t - d] : 0;
            __syncthreads();
            sdata[t] += add;
            __syncthreads();
        }
        int excl = sdata[t] - v;
        int o = sbase + excl;
        if (i < GSEG) { offs[i] = o; cursor[i] = o; }
        __syncthreads();
        if (t == 1023) sbase += sdata[1023];
        __syncthreads();
    }
    if (t == 0) offs[GSEG] = sbase;
}

// ---------------- K2c: scatter row indices into segment-sorted order -----------
__global__ __launch_bounds__(256) void k_scatter_idx(const int* __restrict__ unq,
                                                     int* __restrict__ cursor,
                                                     int* __restrict__ order, int n)
{
    int i = blockIdx.x * 256 + threadIdx.x;
    if (i < n) {
        int pos = atomicAdd(&cursor[unq[i]], 1);
        order[pos] = i;
    }
}

// ---------------- K2d: per-segment gather sum (one wave per segment) -----------
__global__ __launch_bounds__(256) void k_segsum(
    const u16* __restrict__ lin, const float* __restrict__ xyz,
    const int* __restrict__ order, const int* __restrict__ offs,
    const float* __restrict__ scale1, const float* __restrict__ shift1,
    const float* __restrict__ Wp1, const float* __restrict__ bp1,
    float* __restrict__ feat_add, int nseg)
{
    int wave = threadIdx.x >> 6;
    int lane = threadIdx.x & 63;
    int s = blockIdx.x * 4 + wave;
    if (s >= nseg) return;
    int c = lane * 2;
    float w0x = Wp1[c],       w0y = Wp1[128 + c],     w0z = Wp1[256 + c],     b0 = bp1[c];
    float w1x = Wp1[c + 1],   w1y = Wp1[128 + c + 1], w1z = Wp1[256 + c + 1], b1 = bp1[c + 1];
    float sc0 = scale1[c], sh0 = shift1[c];
    float sc1 = scale1[c + 1], sh1 = shift1[c + 1];
    int beg = offs[s], end = offs[s + 1];
    float acc0 = 0.f, acc1 = 0.f;
    for (int r = beg; r < end; ++r) {
        int row = order[r];
        u32 l2 = *(const u32*)(lin + (size_t)row * 128 + c);
        float f0 = __uint_as_float(l2 << 16);
        float f1 = __uint_as_float(l2 & 0xffff0000u);
        float px = floorf(xyz[row * 3 + 0]);
        float py = floorf(xyz[row * 3 + 1]);
        float pz = floorf(xyz[row * 3 + 2]);
        float fe0 = fmaf(f0, sc0, sh0);
        float fe1 = fmaf(f1, sc1, sh1);
        float pw0 = fmaf(px, w0x, fmaf(py, w0y, fmaf(pz, w0z, b0)));
        float pw1 = fmaf(px, w1x, fmaf(py, w1y, fmaf(pz, w1z, b1)));
        acc0 = fmaf(pw0, fe0, acc0);
        acc1 = fmaf(pw1, fe1, acc1);
    }
    float2 st; st.x = acc0; st.y = acc1;
    *(float2*)(feat_add + (size_t)s * 128 + c) = st;
}

// ---------------- K3: BN2 stats over out_pre = pw2*feat - feat_add[unq] ---------
__global__ __launch_bounds__(256) void k_stats2(
    const u16* __restrict__ lin, const float* __restrict__ xyz, const int* __restrict__ unq,
    const float* __restrict__ scale1, const float* __restrict__ shift1,
    const float* __restrict__ Wp2, const float* __restrict__ bp2,
    const float* __restrict__ feat_add,
    float* __restrict__ sum2, float* __restrict__ sumsq2, int n, int iters)
{
    __shared__ float sS[128], sH[128], sW3[384], sB[128], sSum[128], sSq[128];
    int t = threadIdx.x;
    if (t < 128) {
        sS[t] = scale1[t]; sH[t] = shift1[t]; sB[t] = bp2[t];
        sW3[t] = Wp2[t]; sW3[128 + t] = Wp2[128 + t]; sW3[256 + t] = Wp2[256 + t];
        sSum[t] = 0.f; sSq[t] = 0.f;
    }
    __syncthreads();
    int c0 = (t & 15) * 8;
    float ssum[8], ssq[8];
#pragma unroll
    for (int j = 0; j < 8; j++) { ssum[j] = 0.f; ssq[j] = 0.f; }

    for (int it = 0; it < iters; ++it) {
        int row = (blockIdx.x * iters + it) * 16 + (t >> 4);
        if (row >= n) break;
        uint4 l8 = *(const uint4*)(lin + (size_t)row * 128 + c0);
        float f[8];
        unpack8(l8, f);
        float px = floorf(xyz[row * 3 + 0]);
        float py = floorf(xyz[row * 3 + 1]);
        float pz = floorf(xyz[row * 3 + 2]);
        int g = unq[row];
        const float4* fa = (const float4*)(feat_add + (size_t)g * 128 + c0);
        float4 fa0 = fa[0], fa1 = fa[1];
        float fav[8] = {fa0.x, fa0.y, fa0.z, fa0.w, fa1.x, fa1.y, fa1.z, fa1.w};
#pragma unroll
        for (int j = 0; j < 8; j++) {
            int c = c0 + j;
            float fe = fmaf(f[j], sS[c], sH[c]);
            float pw = fmaf(px, sW3[c], fmaf(py, sW3[128 + c], fmaf(pz, sW3[256 + c], sB[c])));
            float o = pw * fe - fav[j];
            ssum[j] += o;
            ssq[j] += o * o;
        }
    }
#pragma unroll
    for (int j = 0; j < 8; j++) {
        atomicAdd(&sSum[c0 + j], ssum[j]);
        atomicAdd(&sSq[c0 + j], ssq[j]);
    }
    __syncthreads();
    if (t < 128) { atomicAdd(&sum2[t], sSum[t]); atomicAdd(&sumsq2[t], sSq[t]); }
}

// ---------------- K4: final out = relu(bn2(out_pre)) ----------------------------
__global__ __launch_bounds__(256) void k_final(
    const u16* __restrict__ lin, const float* __restrict__ xyz, const int* __restrict__ unq,
    const float* __restrict__ scale1, const float* __restrict__ shift1,
    const float* __restrict__ Wp2, const float* __restrict__ bp2,
    const float* __restrict__ feat_add,
    const float* __restrict__ scale2, const float* __restrict__ shift2,
    float* __restrict__ out, int n)
{
    __shared__ float sS[128], sH[128], sW3[384], sB[128], sS2[128], sH2[128];
    int t = threadIdx.x;
    if (t < 128) {
        sS[t] = scale1[t]; sH[t] = shift1[t]; sB[t] = bp2[t];
        sW3[t] = Wp2[t]; sW3[128 + t] = Wp2[128 + t]; sW3[256 + t] = Wp2[256 + t];
        sS2[t] = scale2[t]; sH2[t] = shift2[t];
    }
    __syncthreads();
    int row = blockIdx.x * 16 + (t >> 4);
    if (row >= n) return;
    int c0 = (t & 15) * 8;
    uint4 l8 = *(const uint4*)(lin + (size_t)row * 128 + c0);
    float f[8];
    unpack8(l8, f);
    float px = floorf(xyz[row * 3 + 0]);
    float py = floorf(xyz[row * 3 + 1]);
    float pz = floorf(xyz[row * 3 + 2]);
    int g = unq[row];
    const float4* fa = (const float4*)(feat_add + (size_t)g * 128 + c0);
    float4 fa0 = fa[0], fa1 = fa[1];
    float fav[8] = {fa0.x, fa0.y, fa0.z, fa0.w, fa1.x, fa1.y, fa1.z, fa1.w};
    float o[8];
#pragma unroll
    for (int j = 0; j < 8; j++) {
        int c = c0 + j;
        float fe = fmaf(f[j], sS[c], sH[c]);
        float pw = fmaf(px, sW3[c], fmaf(py, sW3[128 + c], fmaf(pz, sW3[256 + c], sB[c])));
        float v = pw * fe - fav[j];
        v = fmaf(v, sS2[c], sH2[c]);
        o[j] = v > 0.f ? v : 0.f;
    }
    float4 s0, s1;
    s0.x = o[0]; s0.y = o[1]; s0.z = o[2]; s0.w = o[3];
    s1.x = o[4]; s1.y = o[5]; s1.z = o[6]; s1.w = o[7];
    float* op = out + (size_t)row * 128 + c0;
    *(float4*)op = s0;
    *(float4*)(op + 4) = s1;
}

extern "C" void kernel_launch(void* const* d_in, const int* in_sizes, int n_in,
                              void* d_out, int out_size, void* d_ws, size_t ws_size,
                              hipStream_t stream)
{
    const float* xyz      = (const float*)d_in[0];
    const float* feat_all = (const float*)d_in[1];
    const int*   unq      = (const int*)d_in[2];
    const float* W_pre    = (const float*)d_in[3];
    const float* b_pre    = (const float*)d_in[4];
    const float* g1       = (const float*)d_in[5];
    const float* be1      = (const float*)d_in[6];
    const float* Wp1      = (const float*)d_in[7];
    const float* bp1      = (const float*)d_in[8];
    const float* Wp2      = (const float*)d_in[9];
    const float* bp2      = (const float*)d_in[10];
    const float* g2       = (const float*)d_in[11];
    const float* be2      = (const float*)d_in[12];
    (void)n_in; (void)out_size; (void)ws_size;

    const int n = in_sizes[0] / 3;   // 400000

    // workspace layout (256B-aligned chunks)
    char* ws = (char*)d_ws;
    float* stats  = (float*)ws;                 // 1024 floats @ 0
    float* sum1   = stats;       float* sumsq1 = stats + 128;
    float* sum2   = stats + 256; float* sumsq2 = stats + 384;
    float* scale1 = stats + 512; float* shift1 = stats + 640;
    float* scale2 = stats + 768; float* shift2 = stats + 896;
    int*   cnt      = (int*)(ws + 4096);                       // 30000 ints
    int*   offs     = (int*)(ws + 124160);                     // 30001 ints
    int*   cursor   = (int*)(ws + 244224);                     // 30000 ints
    int*   order    = (int*)(ws + 364288);                     // 400000 ints
    float* feat_add = (float*)(ws + 1964544);                  // 30000*128 floats
    u16*   lin      = (u16*)(ws + 17324544);                   // 400000*128 bf16

    // zero stats + cnt (contiguous prefix)
    hipMemsetAsync(d_ws, 0, 124160, stream);

    k_gemm_bn1<<<(n + 63) / 64, 256, 0, stream>>>(feat_all, W_pre, b_pre, lin, sum1, sumsq1, n);
    k_fin<<<1, 128, 0, stream>>>(sum1, sumsq1, g1, be1, scale1, shift1, 1.0f / n);

    k_hist<<<(n + 255) / 256, 256, 0, stream>>>(unq, cnt, n);
    k_scan<<<1, 1024, 0, stream>>>(cnt, offs, cursor);
    k_scatter_idx<<<(n + 255) / 256, 256, 0, stream>>>(unq, cursor, order, n);
    k_segsum<<<(GSEG + 3) / 4, 256, 0, stream>>>(lin, xyz, order, offs, scale1, shift1, Wp1, bp1, feat_add, GSEG);

    int iters = (n + 16 * 2500 - 1) / (16 * 2500);
    k_stats2<<<2500, 256, 0, stream>>>(lin, xyz, unq, scale1, shift1, Wp2, bp2, feat_add, sum2, sumsq2, n, iters);
    k_fin<<<1, 128, 0, stream>>>(sum2, sumsq2, g2, be2, scale2, shift2, 1.0f / n);
    k_final<<<(n + 15) / 16, 256, 0, stream>>>(lin, xyz, unq, scale1, shift1, Wp2, bp2, feat_add, scale2, shift2, (float*)d_out, n);
}

// Round 3
// 650.678 us; speedup vs baseline: 3.1375x; 1.2433x over previous
//
#include <hip/hip_runtime.h>
#include <hip/hip_bf16.h>

typedef unsigned int u32;
typedef unsigned short u16;
typedef __attribute__((ext_vector_type(8))) short short8;
typedef __attribute__((ext_vector_type(4))) float floatx4;

#define COUT 128
#define GSEG 30000
#define BN_EPS 1e-3f

__device__ __forceinline__ u32 f2bf(float x) {
    u32 u = __float_as_uint(x);
    return (u + 0x7fffu + ((u >> 16) & 1u)) >> 16;   // RNE bf16
}
__device__ __forceinline__ float bf2f(u32 b) { return __uint_as_float(b << 16); }

__device__ __forceinline__ void unpack8(uint4 v, float* f) {
    f[0] = __uint_as_float(v.x << 16); f[1] = __uint_as_float(v.x & 0xffff0000u);
    f[2] = __uint_as_float(v.y << 16); f[3] = __uint_as_float(v.y & 0xffff0000u);
    f[4] = __uint_as_float(v.z << 16); f[5] = __uint_as_float(v.z & 0xffff0000u);
    f[6] = __uint_as_float(v.w << 16); f[7] = __uint_as_float(v.w & 0xffff0000u);
}

// ---------------- prep: W -> bf16 hi/lo, transposed [c][k] -------------------
__global__ __launch_bounds__(512) void k_prep_w(
    const float* __restrict__ W, u16* __restrict__ wt_hi, u16* __restrict__ wt_lo)
{
    int t = threadIdx.x;
    for (int f = t; f < 8192; f += 512) {
        int k = f >> 7, c = f & 127;
        float w = W[f];
        u32 hb = f2bf(w);
        float lo = w - bf2f(hb);
        wt_hi[c * 64 + k] = (u16)hb;
        wt_lo[c * 64 + k] = (u16)f2bf(lo);
    }
}

// ---------------- K1: lin = A @ W + b (split-bf16 MFMA) + BN1 stats ----------
// block: 512 thr (8 waves), 128 rows/block. LDS: A hi/lo [128][72], W hi/lo [128][72]
__global__ __launch_bounds__(512) void k_gemm_bn1(
    const float* __restrict__ A, const u16* __restrict__ wt_hi, const u16* __restrict__ wt_lo,
    const float* __restrict__ bias, u16* __restrict__ lin,
    float* __restrict__ sum1, float* __restrict__ sumsq1, int n)
{
    __shared__ union {
        struct { u16 ahi[128 * 72]; u16 alo[128 * 72]; u16 whi[128 * 72]; u16 wlo[128 * 72]; } s;
        u16 pack[128 * 136];           // epilogue repack (aliases dead staging)
    } sm;
    __shared__ float sSum[128], sSq[128];

    const int t = threadIdx.x;
    const int row0 = blockIdx.x * 128;
    if (t < 128) { sSum[t] = 0.f; sSq[t] = 0.f; }

    // stage A: 128x64 fp32 -> bf16 hi/lo
#pragma unroll
    for (int j = 0; j < 4; j++) {
        int f = t + j * 512;               // 2048 float4
        int row = f >> 4, k0 = (f & 15) << 2;
        float4 v = make_float4(0.f, 0.f, 0.f, 0.f);
        if (row0 + row < n) v = *(const float4*)&A[(size_t)(row0 + row) * 64 + k0];
        float vv[4] = {v.x, v.y, v.z, v.w};
        u32 hb[4], lb[4];
#pragma unroll
        for (int i = 0; i < 4; i++) {
            hb[i] = f2bf(vv[i]);
            lb[i] = f2bf(vv[i] - bf2f(hb[i]));
        }
        uint2 ph = make_uint2(hb[0] | (hb[1] << 16), hb[2] | (hb[3] << 16));
        uint2 pl = make_uint2(lb[0] | (lb[1] << 16), lb[2] | (lb[3] << 16));
        *(uint2*)&sm.s.ahi[row * 72 + k0] = ph;
        *(uint2*)&sm.s.alo[row * 72 + k0] = pl;
    }
    // stage W hi/lo (pre-transposed [c][64])
#pragma unroll
    for (int j = 0; j < 2; j++) {
        int f = t + j * 512;               // 1024 uint4 per matrix
        int c = f >> 3, k0 = (f & 7) << 3;
        uint4 vh = *(const uint4*)&wt_hi[f * 8];
        uint4 vl = *(const uint4*)&wt_lo[f * 8];
        *(uint4*)&sm.s.whi[c * 72 + k0] = vh;
        *(uint4*)&sm.s.wlo[c * 72 + k0] = vl;
    }
    __syncthreads();

    const int lane = t & 63, wv = t >> 6;
    const int r = lane & 15, q = lane >> 4;
    const int rw0 = wv * 16;

    // A-row fragments (hi/lo x 2 k-steps)
    short8 arh[2], arl[2];
#pragma unroll
    for (int ks = 0; ks < 2; ks++) {
        arh[ks] = *(const short8*)&sm.s.ahi[(rw0 + r) * 72 + ks * 32 + q * 8];
        arl[ks] = *(const short8*)&sm.s.alo[(rw0 + r) * 72 + ks * 32 + q * 8];
    }

    floatx4 acc[8];
#pragma unroll
    for (int ct = 0; ct < 8; ct++) acc[ct] = (floatx4){0.f, 0.f, 0.f, 0.f};

#pragma unroll
    for (int ct = 0; ct < 8; ct++) {
#pragma unroll
        for (int ks = 0; ks < 2; ks++) {
            short8 wh = *(const short8*)&sm.s.whi[(ct * 16 + r) * 72 + ks * 32 + q * 8];
            short8 wl = *(const short8*)&sm.s.wlo[(ct * 16 + r) * 72 + ks * 32 + q * 8];
            acc[ct] = __builtin_amdgcn_mfma_f32_16x16x32_bf16(arh[ks], wh, acc[ct], 0, 0, 0);
            acc[ct] = __builtin_amdgcn_mfma_f32_16x16x32_bf16(arl[ks], wh, acc[ct], 0, 0, 0);
            acc[ct] = __builtin_amdgcn_mfma_f32_16x16x32_bf16(arh[ks], wl, acc[ct], 0, 0, 0);
        }
    }
    __syncthreads();   // staging dead; sm.pack now usable

    // epilogue: bias, stats, repack bf16 into LDS
#pragma unroll
    for (int ct = 0; ct < 8; ct++) {
        int c = ct * 16 + r;
        float bv = bias[c];
        float ssum = 0.f, ssq = 0.f;
#pragma unroll
        for (int i = 0; i < 4; i++) {
            int lrow = rw0 + q * 4 + i;
            float v = acc[ct][i] + bv;
            if (row0 + lrow >= n) v = 0.f;
            ssum += v; ssq += v * v;
            sm.pack[lrow * 136 + c] = (u16)f2bf(v);
        }
        ssum += __shfl_xor(ssum, 16, 64); ssq += __shfl_xor(ssq, 16, 64);
        ssum += __shfl_xor(ssum, 32, 64); ssq += __shfl_xor(ssq, 32, 64);
        if (lane < 16) { atomicAdd(&sSum[c], ssum); atomicAdd(&sSq[c], ssq); }
    }
    __syncthreads();

    // cooperative coalesced store of lin
#pragma unroll
    for (int j = 0; j < 4; j++) {
        int f = t + j * 512;               // 2048 chunks of 8 bf16
        int row = f >> 4, c0 = (f & 15) << 3;
        if (row0 + row < n) {
            uint4 v = *(const uint4*)&sm.pack[row * 136 + c0];
            *(uint4*)(lin + (size_t)(row0 + row) * 128 + c0) = v;
        }
    }
    if (t < 128) { atomicAdd(&sum1[t], sSum[t]); atomicAdd(&sumsq1[t], sSq[t]); }
}

// ---------------- finalize BN params ----------------
__global__ void k_fin(const float* __restrict__ sum, const float* __restrict__ sumsq,
                      const float* __restrict__ g, const float* __restrict__ be,
                      float* __restrict__ scale, float* __restrict__ shift, float inv_n)
{
    int c = threadIdx.x;
    float mean = sum[c] * inv_n;
    float var = sumsq[c] * inv_n - mean * mean;
    float sc = g[c] * rsqrtf(var + BN_EPS);
    scale[c] = sc;
    shift[c] = be[c] - mean * sc;
}

// ---------------- K2a: histogram of segment ids ----------------
__global__ __launch_bounds__(256) void k_hist(const int* __restrict__ unq,
                                              int* __restrict__ cnt, int n)
{
    int i = blockIdx.x * 256 + threadIdx.x;
    if (i < n) atomicAdd(&cnt[unq[i]], 1);
}

// ---------------- K2b: exclusive scan (wave shuffle scans) ----------------
__global__ __launch_bounds__(1024) void k_scan(const int* __restrict__ cnt,
                                               int* __restrict__ offs,
                                               int* __restrict__ cursor)
{
    __shared__ int wsum[16];
    __shared__ int chunkbase;
    int t = threadIdx.x, lane = t & 63, wv = t >> 6;
    if (t == 0) chunkbase = 0;
    __syncthreads();
    for (int base = 0; base < GSEG; base += 1024) {
        int i = base + t;
        int v = (i < GSEG) ? cnt[i] : 0;
        int x = v;
#pragma unroll
        for (int d = 1; d < 64; d <<= 1) {
            int u = __shfl_up(x, d, 64);
            if (lane >= d) x += u;
        }
        if (lane == 63) wsum[wv] = x;
        __syncthreads();
        if (t < 16) {
            int w = wsum[t];
#pragma unroll
            for (int d = 1; d < 16; d <<= 1) {
                int u = __shfl_up(w, d, 16);
                if (t >= d) w += u;
            }
            wsum[t] = w;
        }
        __syncthreads();
        int woff = wv ? wsum[wv - 1] : 0;
        int excl = chunkbase + woff + x - v;
        if (i < GSEG) { offs[i] = excl; cursor[i] = excl; }
        int total = wsum[15];
        __syncthreads();
        if (t == 0) chunkbase += total;
        __syncthreads();
    }
    if (t == 0) offs[GSEG] = chunkbase;
}

// ---------------- K2c: scatter row indices into segment-sorted order -----------
__global__ __launch_bounds__(256) void k_scatter_idx(const int* __restrict__ unq,
                                                     int* __restrict__ cursor,
                                                     int* __restrict__ order, int n)
{
    int i = blockIdx.x * 256 + threadIdx.x;
    if (i < n) {
        int pos = atomicAdd(&cursor[unq[i]], 1);
        order[pos] = i;
    }
}

// ---------------- K2d: per-segment gather sum (one wave per segment) -----------
__global__ __launch_bounds__(256) void k_segsum(
    const u16* __restrict__ lin, const float* __restrict__ xyz,
    const int* __restrict__ order, const int* __restrict__ offs,
    const float* __restrict__ scale1, const float* __restrict__ shift1,
    const float* __restrict__ Wp1, const float* __restrict__ bp1,
    float* __restrict__ feat_add, int nseg)
{
    int wave = threadIdx.x >> 6;
    int lane = threadIdx.x & 63;
    int s = blockIdx.x * 4 + wave;
    if (s >= nseg) return;
    int c = lane * 2;
    float w0x = Wp1[c],     w0y = Wp1[128 + c],     w0z = Wp1[256 + c],     b0 = bp1[c];
    float w1x = Wp1[c + 1], w1y = Wp1[128 + c + 1], w1z = Wp1[256 + c + 1], b1 = bp1[c + 1];
    float sc0 = scale1[c], sh0 = shift1[c];
    float sc1 = scale1[c + 1], sh1 = shift1[c + 1];
    int beg = offs[s], end = offs[s + 1];
    float acc0 = 0.f, acc1 = 0.f;
    int rr = beg;
    for (; rr + 2 <= end; rr += 2) {
        int rowA = order[rr], rowB = order[rr + 1];
        u32 lA = *(const u32*)(lin + (size_t)rowA * 128 + c);
        u32 lB = *(const u32*)(lin + (size_t)rowB * 128 + c);
        float pxA = floorf(xyz[rowA * 3]), pyA = floorf(xyz[rowA * 3 + 1]), pzA = floorf(xyz[rowA * 3 + 2]);
        float pxB = floorf(xyz[rowB * 3]), pyB = floorf(xyz[rowB * 3 + 1]), pzB = floorf(xyz[rowB * 3 + 2]);
        float feA0 = fmaf(__uint_as_float(lA << 16), sc0, sh0);
        float feA1 = fmaf(__uint_as_float(lA & 0xffff0000u), sc1, sh1);
        float feB0 = fmaf(__uint_as_float(lB << 16), sc0, sh0);
        float feB1 = fmaf(__uint_as_float(lB & 0xffff0000u), sc1, sh1);
        float pwA0 = fmaf(pxA, w0x, fmaf(pyA, w0y, fmaf(pzA, w0z, b0)));
        float pwA1 = fmaf(pxA, w1x, fmaf(pyA, w1y, fmaf(pzA, w1z, b1)));
        float pwB0 = fmaf(pxB, w0x, fmaf(pyB, w0y, fmaf(pzB, w0z, b0)));
        float pwB1 = fmaf(pxB, w1x, fmaf(pyB, w1y, fmaf(pzB, w1z, b1)));
        acc0 = fmaf(pwA0, feA0, acc0); acc1 = fmaf(pwA1, feA1, acc1);
        acc0 = fmaf(pwB0, feB0, acc0); acc1 = fmaf(pwB1, feB1, acc1);
    }
    if (rr < end) {
        int row = order[rr];
        u32 l2 = *(const u32*)(lin + (size_t)row * 128 + c);
        float px = floorf(xyz[row * 3]), py = floorf(xyz[row * 3 + 1]), pz = floorf(xyz[row * 3 + 2]);
        float fe0 = fmaf(__uint_as_float(l2 << 16), sc0, sh0);
        float fe1 = fmaf(__uint_as_float(l2 & 0xffff0000u), sc1, sh1);
        float pw0 = fmaf(px, w0x, fmaf(py, w0y, fmaf(pz, w0z, b0)));
        float pw1 = fmaf(px, w1x, fmaf(py, w1y, fmaf(pz, w1z, b1)));
        acc0 = fmaf(pw0, fe0, acc0); acc1 = fmaf(pw1, fe1, acc1);
    }
    float2 st; st.x = acc0; st.y = acc1;
    *(float2*)(feat_add + (size_t)s * 128 + c) = st;
}

// ---------------- K3: BN2 stats over out_pre = pw2*feat - feat_add[unq] ---------
__global__ __launch_bounds__(256) void k_stats2(
    const u16* __restrict__ lin, const float* __restrict__ xyz, const int* __restrict__ unq,
    const float* __restrict__ scale1, const float* __restrict__ shift1,
    const float* __restrict__ Wp2, const float* __restrict__ bp2,
    const float* __restrict__ feat_add,
    float* __restrict__ sum2, float* __restrict__ sumsq2, int n, int iters)
{
    __shared__ float sS[128], sH[128], sW3[384], sB[128], sSum[128], sSq[128];
    int t = threadIdx.x;
    if (t < 128) {
        sS[t] = scale1[t]; sH[t] = shift1[t]; sB[t] = bp2[t];
        sW3[t] = Wp2[t]; sW3[128 + t] = Wp2[128 + t]; sW3[256 + t] = Wp2[256 + t];
        sSum[t] = 0.f; sSq[t] = 0.f;
    }
    __syncthreads();
    int c0 = (t & 15) * 8;
    float ssum[8], ssq[8];
#pragma unroll
    for (int j = 0; j < 8; j++) { ssum[j] = 0.f; ssq[j] = 0.f; }

    for (int it = 0; it < iters; ++it) {
        int row = (blockIdx.x * iters + it) * 16 + (t >> 4);
        if (row >= n) break;
        uint4 l8 = *(const uint4*)(lin + (size_t)row * 128 + c0);
        float f[8];
        unpack8(l8, f);
        float px = floorf(xyz[row * 3 + 0]);
        float py = floorf(xyz[row * 3 + 1]);
        float pz = floorf(xyz[row * 3 + 2]);
        int g = unq[row];
        const float4* fa = (const float4*)(feat_add + (size_t)g * 128 + c0);
        float4 fa0 = fa[0], fa1 = fa[1];
        float fav[8] = {fa0.x, fa0.y, fa0.z, fa0.w, fa1.x, fa1.y, fa1.z, fa1.w};
#pragma unroll
        for (int j = 0; j < 8; j++) {
            int c = c0 + j;
            float fe = fmaf(f[j], sS[c], sH[c]);
            float pw = fmaf(px, sW3[c], fmaf(py, sW3[128 + c], fmaf(pz, sW3[256 + c], sB[c])));
            float o = pw * fe - fav[j];
            ssum[j] += o;
            ssq[j] += o * o;
        }
    }
#pragma unroll
    for (int j = 0; j < 8; j++) {
        atomicAdd(&sSum[c0 + j], ssum[j]);
        atomicAdd(&sSq[c0 + j], ssq[j]);
    }
    __syncthreads();
    if (t < 128) { atomicAdd(&sum2[t], sSum[t]); atomicAdd(&sumsq2[t], sSq[t]); }
}

// ---------------- K4: final out = relu(bn2(out_pre)) ----------------------------
__global__ __launch_bounds__(256) void k_final(
    const u16* __restrict__ lin, const float* __restrict__ xyz, const int* __restrict__ unq,
    const float* __restrict__ scale1, const float* __restrict__ shift1,
    const float* __restrict__ Wp2, const float* __restrict__ bp2,
    const float* __restrict__ feat_add,
    const float* __restrict__ scale2, const float* __restrict__ shift2,
    float* __restrict__ out, int n)
{
    __shared__ float sS[128], sH[128], sW3[384], sB[128], sS2[128], sH2[128];
    int t = threadIdx.x;
    if (t < 128) {
        sS[t] = scale1[t]; sH[t] = shift1[t]; sB[t] = bp2[t];
        sW3[t] = Wp2[t]; sW3[128 + t] = Wp2[128 + t]; sW3[256 + t] = Wp2[256 + t];
        sS2[t] = scale2[t]; sH2[t] = shift2[t];
    }
    __syncthreads();
    int row = blockIdx.x * 16 + (t >> 4);
    if (row >= n) return;
    int c0 = (t & 15) * 8;
    uint4 l8 = *(const uint4*)(lin + (size_t)row * 128 + c0);
    float f[8];
    unpack8(l8, f);
    float px = floorf(xyz[row * 3 + 0]);
    float py = floorf(xyz[row * 3 + 1]);
    float pz = floorf(xyz[row * 3 + 2]);
    int g = unq[row];
    const float4* fa = (const float4*)(feat_add + (size_t)g * 128 + c0);
    float4 fa0 = fa[0], fa1 = fa[1];
    float fav[8] = {fa0.x, fa0.y, fa0.z, fa0.w, fa1.x, fa1.y, fa1.z, fa1.w};
    float o[8];
#pragma unroll
    for (int j = 0; j < 8; j++) {
        int c = c0 + j;
        float fe = fmaf(f[j], sS[c], sH[c]);
        float pw = fmaf(px, sW3[c], fmaf(py, sW3[128 + c], fmaf(pz, sW3[256 + c], sB[c])));
        float v = pw * fe - fav[j];
        v = fmaf(v, sS2[c], sH2[c]);
        o[j] = v > 0.f ? v : 0.f;
    }
    float4 s0, s1;
    s0.x = o[0]; s0.y = o[1]; s0.z = o[2]; s0.w = o[3];
    s1.x = o[4]; s1.y = o[5]; s1.z = o[6]; s1.w = o[7];
    float* op = out + (size_t)row * 128 + c0;
    *(float4*)op = s0;
    *(float4*)(op + 4) = s1;
}

extern "C" void kernel_launch(void* const* d_in, const int* in_sizes, int n_in,
                              void* d_out, int out_size, void* d_ws, size_t ws_size,
                              hipStream_t stream)
{
    const float* xyz      = (const float*)d_in[0];
    const float* feat_all = (const float*)d_in[1];
    const int*   unq      = (const int*)d_in[2];
    const float* W_pre    = (const float*)d_in[3];
    const float* b_pre    = (const float*)d_in[4];
    const float* g1       = (const float*)d_in[5];
    const float* be1      = (const float*)d_in[6];
    const float* Wp1      = (const float*)d_in[7];
    const float* bp1      = (const float*)d_in[8];
    const float* Wp2      = (const float*)d_in[9];
    const float* bp2      = (const float*)d_in[10];
    const float* g2       = (const float*)d_in[11];
    const float* be2      = (const float*)d_in[12];
    (void)n_in; (void)out_size; (void)ws_size;

    const int n = in_sizes[0] / 3;   // 400000

    char* ws = (char*)d_ws;
    float* stats  = (float*)ws;                 // 1024 floats @ 0
    float* sum1   = stats;       float* sumsq1 = stats + 128;
    float* sum2   = stats + 256; float* sumsq2 = stats + 384;
    float* scale1 = stats + 512; float* shift1 = stats + 640;
    float* scale2 = stats + 768; float* shift2 = stats + 896;
    int*   cnt      = (int*)(ws + 4096);                       // 30000 ints
    int*   offs     = (int*)(ws + 124160);                     // 30001 ints
    int*   cursor   = (int*)(ws + 244224);                     // 30000 ints
    // Wt_hi/Wt_lo live in the order region: dead once k_scatter_idx runs
    u16*   wt_hi    = (u16*)(ws + 364288);                     // 8192 u16
    u16*   wt_lo    = (u16*)(ws + 380672);                     // 8192 u16
    int*   order    = (int*)(ws + 364288);                     // 400000 ints (overwrites wt after gemm)
    float* feat_add = (float*)(ws + 1964544);                  // 30000*128 floats
    u16*   lin      = (u16*)(ws + 17324544);                   // 400000*128 bf16

    hipMemsetAsync(d_ws, 0, 124160, stream);   // stats + cnt

    k_prep_w<<<1, 512, 0, stream>>>(W_pre, wt_hi, wt_lo);
    k_gemm_bn1<<<(n + 127) / 128, 512, 0, stream>>>(feat_all, wt_hi, wt_lo, b_pre, lin, sum1, sumsq1, n);
    k_fin<<<1, 128, 0, stream>>>(sum1, sumsq1, g1, be1, scale1, shift1, 1.0f / n);

    k_hist<<<(n + 255) / 256, 256, 0, stream>>>(unq, cnt, n);
    k_scan<<<1, 1024, 0, stream>>>(cnt, offs, cursor);
    k_scatter_idx<<<(n + 255) / 256, 256, 0, stream>>>(unq, cursor, order, n);
    k_segsum<<<(GSEG + 3) / 4, 256, 0, stream>>>(lin, xyz, order, offs, scale1, shift1, Wp1, bp1, feat_add, GSEG);

    int iters = (n + 16 * 2500 - 1) / (16 * 2500);
    k_stats2<<<2500, 256, 0, stream>>>(lin, xyz, unq, scale1, shift1, Wp2, bp2, feat_add, sum2, sumsq2, n, iters);
    k_fin<<<1, 128, 0, stream>>>(sum2, sumsq2, g2, be2, scale2, shift2, 1.0f / n);
    k_final<<<(n + 15) / 16, 256, 0, stream>>>(lin, xyz, unq, scale1, shift1, Wp2, bp2, feat_add, scale2, shift2, (float*)d_out, n);
}